// Round 6
// baseline (726.842 us; speedup 1.0000x reference)
//
#include <hip/hip_runtime.h>

// ---------------- types ----------------
typedef __bf16 bf16x8 __attribute__((ext_vector_type(8)));
typedef float f32x4 __attribute__((ext_vector_type(4)));

__device__ __forceinline__ unsigned short f2bf(float f) {
    unsigned int u = __builtin_bit_cast(unsigned int, f);
    u += 0x7FFFu + ((u >> 16) & 1u);
    return (unsigned short)(u >> 16);
}

// ---------------- weight f32 -> bf16 conversion ----------------
__global__ void cvt_kernel(const float* __restrict__ in,
                           unsigned short* __restrict__ out, long n4) {
    long i = (long)blockIdx.x * blockDim.x + threadIdx.x;
    long stride = (long)gridDim.x * blockDim.x;
    for (; i < n4; i += stride) {
        float4 v = ((const float4*)in)[i];
        ushort4 o;
        o.x = f2bf(v.x); o.y = f2bf(v.y); o.z = f2bf(v.z); o.w = f2bf(v.w);
        ((ushort4*)out)[i] = o;
    }
}

// ---------------- fused 2-token attention -> h0 (bf16) ----------------
__global__ __launch_bounds__(256) void attn_kernel(
    const float* __restrict__ x1, const float* __restrict__ x2,
    unsigned short* __restrict__ h) {
    const int D = 1024;
    const int lane = threadIdx.x & 63;
    const int wave = threadIdx.x >> 6;
    const long row = (long)blockIdx.x * 4 + wave;
    const float4* p1 = (const float4*)(x1 + row * D);
    const float4* p2 = (const float4*)(x2 + row * D);
    float4 v1[4], v2[4];
    float s11 = 0.f, s12 = 0.f, s22 = 0.f;
#pragma unroll
    for (int j = 0; j < 4; ++j) {
        v1[j] = p1[lane + 64 * j];
        v2[j] = p2[lane + 64 * j];
        s11 += v1[j].x * v1[j].x + v1[j].y * v1[j].y + v1[j].z * v1[j].z + v1[j].w * v1[j].w;
        s12 += v1[j].x * v2[j].x + v1[j].y * v2[j].y + v1[j].z * v2[j].z + v1[j].w * v2[j].w;
        s22 += v2[j].x * v2[j].x + v2[j].y * v2[j].y + v2[j].z * v2[j].z + v2[j].w * v2[j].w;
    }
#pragma unroll
    for (int off = 1; off < 64; off <<= 1) {
        s11 += __shfl_xor(s11, off);
        s12 += __shfl_xor(s12, off);
        s22 += __shfl_xor(s22, off);
    }
    const float a00 = 1.f / (1.f + expf((s12 - s11) * (1.f / 32.f)));
    const float a10 = 1.f / (1.f + expf((s22 - s12) * (1.f / 32.f)));
    const float a01 = 1.f - a00, a11 = 1.f - a10;
    unsigned short* h0 = h + row * 2048;
#pragma unroll
    for (int j = 0; j < 4; ++j) {
        const int f = lane + 64 * j;
        ushort4 o0, o1;
        o0.x = f2bf(a00 * v1[j].x + a01 * v2[j].x);
        o0.y = f2bf(a00 * v1[j].y + a01 * v2[j].y);
        o0.z = f2bf(a00 * v1[j].z + a01 * v2[j].z);
        o0.w = f2bf(a00 * v1[j].w + a01 * v2[j].w);
        o1.x = f2bf(a10 * v1[j].x + a11 * v2[j].x);
        o1.y = f2bf(a10 * v1[j].y + a11 * v2[j].y);
        o1.z = f2bf(a10 * v1[j].z + a11 * v2[j].z);
        o1.w = f2bf(a10 * v1[j].w + a11 * v2[j].w);
        ((ushort4*)(h0))[f] = o0;
        ((ushort4*)(h0 + 1024))[f] = o1;
    }
}

// ---------------- 256x256 8-phase GEMM: C = act(A[M,K] * Bw[N,K]^T + bias) ----
// BM=BN=256, BK=64, 8 waves (2Mx4N), 128 KiB LDS = 2 K-tile dbuf.
// Fragment READ-AHEAD: every phase issues the NEXT phase's ds_reads (ping-pong
// A-sets; B persists per tile), so MFMA never waits on in-phase LDS latency.
// vmcnt(0)+mid-barrier at P4/P8 start gates cross-tile read-ahead (cross-wave
// safe: VMW precedes a shared barrier that precedes consumer reads).
#define BAR   __builtin_amdgcn_s_barrier()
#define VMW0  asm volatile("s_waitcnt vmcnt(0)" ::: "memory")
#define PRIO1 __builtin_amdgcn_s_setprio(1)
#define PRIO0 __builtin_amdgcn_s_setprio(0)

#define MM03(kk, AR)                                                           \
  _Pragma("unroll") for (int n = 0; n < 4; ++n)                                \
  _Pragma("unroll") for (int mq = 0; mq < 4; ++mq)                             \
    acc[mq][n] = __builtin_amdgcn_mfma_f32_16x16x32_bf16(                      \
        Bf[n][kk], AR[mq], acc[mq][n], 0, 0, 0);
#define MM47(kk, AR)                                                           \
  _Pragma("unroll") for (int n = 0; n < 4; ++n)                                \
  _Pragma("unroll") for (int mq = 0; mq < 4; ++mq)                             \
    acc[4 + mq][n] = __builtin_amdgcn_mfma_f32_16x16x32_bf16(                  \
        Bf[n][kk], AR[mq], acc[4 + mq][n], 0, 0, 0);

template <bool RELU, typename OT>
__global__ __launch_bounds__(512, 2) void gemm256(
    const unsigned short* __restrict__ A,   // [M,K] bf16 (activations)
    const unsigned short* __restrict__ Bw,  // [N,K] bf16 (weights)
    const float* __restrict__ bias,         // [N]
    OT* __restrict__ C,                     // [M,N]
    int N, int K) {
    __shared__ __align__(16) unsigned short lds[65536];  // 128 KiB: T0|T1
    const int tid = threadIdx.x;
    const int lane = tid & 63, wave = tid >> 6;
    const int wm = wave >> 2, wn = wave & 3;
    const int fr = lane & 15, fq = lane >> 4;

    // XCD-swizzled 1D block id -> (bm, bn)
    const int cpx = (int)gridDim.x >> 3;
    const int swz = ((int)blockIdx.x & 7) * cpx + ((int)blockIdx.x >> 3);
    const int bm = swz & 63;
    const int bn = swz >> 6;
    const long m0 = (long)bm * 256, n0 = (long)bn * 256;

    // LDS read bases (byte offsets); kk=1 address = kk=0 address ^ 64.
    const int x0 = fq ^ (fr & 7);
    const int lane_base = fr * 128 + x0 * 16;
    const int aBase = wm * 16384 + lane_base;
    const int bBase = 32768 + (wn >> 1) * 16384 + (wn & 1) * 8192 + lane_base;
    const char* ldsc = (const char*)lds;

    // staging: per-lane pre-swizzled global source offset (same for A and B)
    const int l3 = lane >> 3, l7 = lane & 7;
    const long rowb = (long)K * 2;
    const long lane_src = (long)l3 * rowb + ((l7 ^ l3) << 4);
    const char* Abl = (const char*)A + m0 * rowb + lane_src;
    const char* Bbl = (const char*)Bw + n0 * rowb + lane_src;

    auto stage = [&](const char* mb, int matOff, int hf, int kt, int T) {
#pragma unroll
        for (int r = 0; r < 2; ++r) {
            const int W = r * 8 + wave;
            const char* src = mb + (long)(hf * 128 + W * 8) * rowb + kt * 128;
            __builtin_amdgcn_global_load_lds(
                (const __attribute__((address_space(1))) void*)src,
                (__attribute__((address_space(3))) void*)((char*)lds +
                    (T * 65536 + matOff + hf * 16384 + W * 1024)),
                16, 0, 0);
        }
    };

    f32x4 acc[8][4] = {};
    bf16x8 Bf[4][2], Ap[4], Aq[4];

    auto rdB = [&](int boff, int kk) {
#pragma unroll
        for (int n = 0; n < 4; ++n)
            Bf[n][kk] = *(const bf16x8*)(ldsc + boff + (bBase ^ (kk << 6)) + n * 2048);
    };
    auto rdA03 = [&](int boff, int kk, bf16x8 (&D)[4]) {
#pragma unroll
        for (int m = 0; m < 4; ++m)
            D[m] = *(const bf16x8*)(ldsc + boff + (aBase ^ (kk << 6)) + m * 2048);
    };
    auto rdA47 = [&](int boff, int kk, bf16x8 (&D)[4]) {
#pragma unroll
        for (int m = 0; m < 4; ++m)
            D[m] = *(const bf16x8*)(ldsc + boff + (aBase ^ (kk << 6)) + (m + 4) * 2048);
    };

    // ---- prologue: tile0 (A+B) -> T0; retire; read F1 frags ahead ----
    stage(Abl, 0,     0, 0, 0); stage(Abl, 0,     1, 0, 0);
    stage(Bbl, 32768, 0, 0, 0); stage(Bbl, 32768, 1, 0, 0);
    VMW0;
    BAR;
    rdB(0, 0); rdA03(0, 0, Ap);      // F1 (tile0 kk0 m0-3)

    const int NT = K >> 6;       // K-tiles
    const int NIT = NT >> 1;     // iterations, 2 K-tiles each
    for (int i = 0; i < NIT; ++i) {
        const int o = 2 * i + 1, e2 = 2 * i + 2;
        const bool g = (i + 1 < NIT);

        // P1: ahead F2 (T0 kk1); stage A(o)->T1; MFMA F1
        rdB(0, 1); rdA03(0, 1, Aq);
        stage(Abl, 0, 0, o, 1); stage(Abl, 0, 1, o, 1);
        PRIO1; MM03(0, Ap); PRIO0; BAR;

        // P2: ahead F3 (T0 A4-7 kk0); stage B(o)->T1; MFMA F2
        rdA47(0, 0, Ap);
        stage(Bbl, 32768, 0, o, 1); stage(Bbl, 32768, 1, o, 1);
        PRIO1; MM03(1, Aq); PRIO0; BAR;

        // P3: ahead F4 (T0 A4-7 kk1); MFMA F3
        rdA47(0, 1, Aq);
        PRIO1; MM47(0, Ap); PRIO0; BAR;

        // P4: retire T1 stages; mid-barrier; ahead F5 (T1 kk0); MFMA F4
        VMW0; BAR;
        rdB(65536, 0); rdA03(65536, 0, Ap);
        PRIO1; MM47(1, Aq); PRIO0; BAR;

        // P5: ahead F6 (T1 kk1); stage A(e2)->T0; MFMA F5
        rdB(65536, 1); rdA03(65536, 1, Aq);
        if (g) { stage(Abl, 0, 0, e2, 0); stage(Abl, 0, 1, e2, 0); }
        PRIO1; MM03(0, Ap); PRIO0; BAR;

        // P6: ahead F7 (T1 A4-7 kk0); stage B(e2)->T0; MFMA F6
        rdA47(65536, 0, Ap);
        if (g) { stage(Bbl, 32768, 0, e2, 0); stage(Bbl, 32768, 1, e2, 0); }
        PRIO1; MM03(1, Aq); PRIO0; BAR;

        // P7: ahead F8 (T1 A4-7 kk1); MFMA F7
        rdA47(65536, 1, Aq);
        PRIO1; MM47(0, Ap); PRIO0; BAR;

        // P8: retire T0 stages; mid-barrier; ahead F1-next (T0 kk0); MFMA F8
        VMW0; BAR;
        if (g) { rdB(0, 0); rdA03(0, 0, Ap); }
        PRIO1; MM47(1, Aq); PRIO0; BAR;
    }

    // ---- epilogue: swapped layout => lane owns row (fr) x 4 consecutive cols
    const long crow0 = m0 + wm * 128 + fr;
    const long ccol0 = n0 + wn * 64 + fq * 4;
    float4 bv[4];
#pragma unroll
    for (int n = 0; n < 4; ++n) bv[n] = *(const float4*)(bias + ccol0 + n * 16);
#pragma unroll
    for (int m = 0; m < 8; ++m) {
        const long rb = (crow0 + m * 16) * N;
#pragma unroll
        for (int n = 0; n < 4; ++n) {
            float v0 = acc[m][n][0] + bv[n].x;
            float v1 = acc[m][n][1] + bv[n].y;
            float v2 = acc[m][n][2] + bv[n].z;
            float v3 = acc[m][n][3] + bv[n].w;
            if (RELU) {
                v0 = v0 > 0.f ? v0 : 0.f; v1 = v1 > 0.f ? v1 : 0.f;
                v2 = v2 > 0.f ? v2 : 0.f; v3 = v3 > 0.f ? v3 : 0.f;
            }
            if constexpr (sizeof(OT) == 2) {
                uint2 oo;
                oo.x = (unsigned)f2bf(v0) | ((unsigned)f2bf(v1) << 16);
                oo.y = (unsigned)f2bf(v2) | ((unsigned)f2bf(v3) << 16);
                *(uint2*)((unsigned short*)C + rb + ccol0 + n * 16) = oo;
            } else {
                *(float4*)((float*)C + rb + ccol0 + n * 16) =
                    make_float4(v0, v1, v2, v3);
            }
        }
    }
}

// ---------------- launch ----------------
extern "C" void kernel_launch(void* const* d_in, const int* in_sizes, int n_in,
                              void* d_out, int out_size, void* d_ws, size_t ws_size,
                              hipStream_t stream) {
    const float* x1 = (const float*)d_in[0];
    const float* x2 = (const float*)d_in[1];
    const float* Ws = (const float*)d_in[2];   // [4,2048,2048]
    const float* bs = (const float*)d_in[3];   // [4,2048]
    const float* Wl = (const float*)d_in[4];   // [1024,2048]
    const float* bl = (const float*)d_in[5];   // [1024]
    float* out = (float*)d_out;                // [16384,1024]

    char* ws = (char*)d_ws;
    unsigned short* hA  = (unsigned short*)(ws);                  // 64 MiB
    unsigned short* hB  = (unsigned short*)(ws + (67108864L));    // 64 MiB
    unsigned short* Wbf = (unsigned short*)(ws + (134217728L));   // 32 MiB
    unsigned short* Wlb = (unsigned short*)(ws + (167772160L));   // 4 MiB

    cvt_kernel<<<2048, 256, 0, stream>>>(Ws, Wbf, 4L * 2048 * 2048 / 4);
    cvt_kernel<<<512, 256, 0, stream>>>(Wl, Wlb, 1024L * 2048 / 4);

    attn_kernel<<<16384 / 4, 256, 0, stream>>>(x1, x2, hA);

    // MLP: 4x relu GEMM (bf16 ping-pong) + final GEMM (f32 out)
    gemm256<true, unsigned short><<<512, 512, 0, stream>>>(hA, Wbf + 0L * 2048 * 2048, bs + 0 * 2048, hB, 2048, 2048);
    gemm256<true, unsigned short><<<512, 512, 0, stream>>>(hB, Wbf + 1L * 2048 * 2048, bs + 1 * 2048, hA, 2048, 2048);
    gemm256<true, unsigned short><<<512, 512, 0, stream>>>(hA, Wbf + 2L * 2048 * 2048, bs + 2 * 2048, hB, 2048, 2048);
    gemm256<true, unsigned short><<<512, 512, 0, stream>>>(hB, Wbf + 3L * 2048 * 2048, bs + 3 * 2048, hA, 2048, 2048);
    gemm256<false, float><<<256, 512, 0, stream>>>(hA, Wlb, bl, out, 1024, 2048);
}

// Round 7
// 690.423 us; speedup vs baseline: 1.0527x; 1.0527x over previous
//
#include <hip/hip_runtime.h>

// ---------------- types ----------------
typedef __bf16 bf16x8 __attribute__((ext_vector_type(8)));
typedef float f32x4 __attribute__((ext_vector_type(4)));

__device__ __forceinline__ unsigned short f2bf(float f) {
    unsigned int u = __builtin_bit_cast(unsigned int, f);
    u += 0x7FFFu + ((u >> 16) & 1u);
    return (unsigned short)(u >> 16);
}

// ---------------- weight f32 -> bf16 conversion ----------------
__global__ void cvt_kernel(const float* __restrict__ in,
                           unsigned short* __restrict__ out, long n4) {
    long i = (long)blockIdx.x * blockDim.x + threadIdx.x;
    long stride = (long)gridDim.x * blockDim.x;
    for (; i < n4; i += stride) {
        float4 v = ((const float4*)in)[i];
        ushort4 o;
        o.x = f2bf(v.x); o.y = f2bf(v.y); o.z = f2bf(v.z); o.w = f2bf(v.w);
        ((ushort4*)out)[i] = o;
    }
}

// ---------------- fused 2-token attention -> h0 (bf16) ----------------
__global__ __launch_bounds__(256) void attn_kernel(
    const float* __restrict__ x1, const float* __restrict__ x2,
    unsigned short* __restrict__ h) {
    const int D = 1024;
    const int lane = threadIdx.x & 63;
    const int wave = threadIdx.x >> 6;
    const long row = (long)blockIdx.x * 4 + wave;
    const float4* p1 = (const float4*)(x1 + row * D);
    const float4* p2 = (const float4*)(x2 + row * D);
    float4 v1[4], v2[4];
    float s11 = 0.f, s12 = 0.f, s22 = 0.f;
#pragma unroll
    for (int j = 0; j < 4; ++j) {
        v1[j] = p1[lane + 64 * j];
        v2[j] = p2[lane + 64 * j];
        s11 += v1[j].x * v1[j].x + v1[j].y * v1[j].y + v1[j].z * v1[j].z + v1[j].w * v1[j].w;
        s12 += v1[j].x * v2[j].x + v1[j].y * v2[j].y + v1[j].z * v2[j].z + v1[j].w * v2[j].w;
        s22 += v2[j].x * v2[j].x + v2[j].y * v2[j].y + v2[j].z * v2[j].z + v2[j].w * v2[j].w;
    }
#pragma unroll
    for (int off = 1; off < 64; off <<= 1) {
        s11 += __shfl_xor(s11, off);
        s12 += __shfl_xor(s12, off);
        s22 += __shfl_xor(s22, off);
    }
    const float a00 = 1.f / (1.f + expf((s12 - s11) * (1.f / 32.f)));
    const float a10 = 1.f / (1.f + expf((s22 - s12) * (1.f / 32.f)));
    const float a01 = 1.f - a00, a11 = 1.f - a10;
    unsigned short* h0 = h + row * 2048;
#pragma unroll
    for (int j = 0; j < 4; ++j) {
        const int f = lane + 64 * j;
        ushort4 o0, o1;
        o0.x = f2bf(a00 * v1[j].x + a01 * v2[j].x);
        o0.y = f2bf(a00 * v1[j].y + a01 * v2[j].y);
        o0.z = f2bf(a00 * v1[j].z + a01 * v2[j].z);
        o0.w = f2bf(a00 * v1[j].w + a01 * v2[j].w);
        o1.x = f2bf(a10 * v1[j].x + a11 * v2[j].x);
        o1.y = f2bf(a10 * v1[j].y + a11 * v2[j].y);
        o1.z = f2bf(a10 * v1[j].z + a11 * v2[j].z);
        o1.w = f2bf(a10 * v1[j].w + a11 * v2[j].w);
        ((ushort4*)(h0))[f] = o0;
        ((ushort4*)(h0 + 1024))[f] = o1;
    }
}

// ---------------- 256x256 8-phase GEMM: C = act(A[M,K] * Bw[N,K]^T + bias) ----
// BM=BN=256, BK=64, 8 waves (2Mx4N), 128 KiB LDS = 2 K-tile dbuf.
// Read-ahead (frags read one phase before use, ping-pong Ap/Aq) + COUNTED
// vmcnt(4) at P4/P8 (retired loads are 2-3 phases old; 4 stay in flight).
// LGKM0 at P3/P7 ends frees the buffer for next-phase staging (cost ~0:
// the guarded reads had a full MFMA cluster to complete).
#define BAR   __builtin_amdgcn_s_barrier()
#define LGKM0 asm volatile("s_waitcnt lgkmcnt(0)" ::: "memory")
#define VMW4  asm volatile("s_waitcnt vmcnt(4)" ::: "memory")
#define VMW0  asm volatile("s_waitcnt vmcnt(0)" ::: "memory")
#define PRIO1 __builtin_amdgcn_s_setprio(1)
#define PRIO0 __builtin_amdgcn_s_setprio(0)

#define MM03(kk, AR)                                                           \
  _Pragma("unroll") for (int n = 0; n < 4; ++n)                                \
  _Pragma("unroll") for (int mq = 0; mq < 4; ++mq)                             \
    acc[mq][n] = __builtin_amdgcn_mfma_f32_16x16x32_bf16(                      \
        Bf[n][kk], AR[mq], acc[mq][n], 0, 0, 0);
#define MM47(kk, AR)                                                           \
  _Pragma("unroll") for (int n = 0; n < 4; ++n)                                \
  _Pragma("unroll") for (int mq = 0; mq < 4; ++mq)                             \
    acc[4 + mq][n] = __builtin_amdgcn_mfma_f32_16x16x32_bf16(                  \
        Bf[n][kk], AR[mq], acc[4 + mq][n], 0, 0, 0);

template <bool RELU, typename OT>
__global__ __launch_bounds__(512, 2) void gemm256(
    const unsigned short* __restrict__ A,   // [M,K] bf16 (activations)
    const unsigned short* __restrict__ Bw,  // [N,K] bf16 (weights)
    const float* __restrict__ bias,         // [N]
    OT* __restrict__ C,                     // [M,N]
    int N, int K) {
    __shared__ __align__(16) unsigned short lds[65536];  // 128 KiB: T0|T1
    const int tid = threadIdx.x;
    const int lane = tid & 63, wave = tid >> 6;
    const int wm = wave >> 2, wn = wave & 3;
    const int fr = lane & 15, fq = lane >> 4;

    // XCD-swizzled 1D block id -> (bm, bn)
    const int cpx = (int)gridDim.x >> 3;
    const int swz = ((int)blockIdx.x & 7) * cpx + ((int)blockIdx.x >> 3);
    const int bm = swz & 63;
    const int bn = swz >> 6;
    const long m0 = (long)bm * 256, n0 = (long)bn * 256;

    // LDS read bases (byte offsets); kk=1 address = kk=0 address ^ 64.
    const int x0 = fq ^ (fr & 7);
    const int lane_base = fr * 128 + x0 * 16;
    const int aBase = wm * 16384 + lane_base;
    const int bBase = 32768 + (wn >> 1) * 16384 + (wn & 1) * 8192 + lane_base;
    const char* ldsc = (const char*)lds;

    // staging: per-lane pre-swizzled global source offset (same for A and B)
    const int l3 = lane >> 3, l7 = lane & 7;
    const long rowb = (long)K * 2;
    const long lane_src = (long)l3 * rowb + ((l7 ^ l3) << 4);
    const char* Abl = (const char*)A + m0 * rowb + lane_src;
    const char* Bbl = (const char*)Bw + n0 * rowb + lane_src;

    auto stage = [&](const char* mb, int matOff, int hf, int kt, int T) {
#pragma unroll
        for (int r = 0; r < 2; ++r) {
            const int W = r * 8 + wave;
            const char* src = mb + (long)(hf * 128 + W * 8) * rowb + kt * 128;
            __builtin_amdgcn_global_load_lds(
                (const __attribute__((address_space(1))) void*)src,
                (__attribute__((address_space(3))) void*)((char*)lds +
                    (T * 65536 + matOff + hf * 16384 + W * 1024)),
                16, 0, 0);
        }
    };

    f32x4 acc[8][4] = {};
    bf16x8 Bf[4][2], Ap[4], Aq[4];

    auto rdB = [&](int boff, int kk) {
#pragma unroll
        for (int n = 0; n < 4; ++n)
            Bf[n][kk] = *(const bf16x8*)(ldsc + boff + (bBase ^ (kk << 6)) + n * 2048);
    };
    auto rdA03 = [&](int boff, int kk, bf16x8 (&D)[4]) {
#pragma unroll
        for (int m = 0; m < 4; ++m)
            D[m] = *(const bf16x8*)(ldsc + boff + (aBase ^ (kk << 6)) + m * 2048);
    };
    auto rdA47 = [&](int boff, int kk, bf16x8 (&D)[4]) {
#pragma unroll
        for (int m = 0; m < 4; ++m)
            D[m] = *(const bf16x8*)(ldsc + boff + (aBase ^ (kk << 6)) + (m + 4) * 2048);
    };

    // ---- prologue: tile0 (A+B) -> T0; drain (one-time); read F1 ahead ----
    stage(Abl, 0,     0, 0, 0); stage(Abl, 0,     1, 0, 0);
    stage(Bbl, 32768, 0, 0, 0); stage(Bbl, 32768, 1, 0, 0);
    VMW0;
    BAR;
    rdB(0, 0); rdA03(0, 0, Ap);      // F1 (tile0 kk0 m0-3)

    const int NT = K >> 6;       // K-tiles
    const int NIT = NT >> 1;     // iterations, 2 K-tiles each
    for (int i = 0; i < NIT; ++i) {
        const int o = 2 * i + 1, e2 = 2 * i + 2, t3 = 2 * i + 3;
        const bool g = (i + 1 < NIT);

        // P1: ahead F2 (T0 kk1); stage A(o)->T1; MFMA F1
        rdB(0, 1); rdA03(0, 1, Aq);
        stage(Abl, 0, 0, o, 1); stage(Abl, 0, 1, o, 1);
        PRIO1; MM03(0, Ap); PRIO0; BAR;

        // P2: ahead F3 (T0 A4-7 kk0); stage B(o)->T1; MFMA F2
        rdA47(0, 0, Ap);
        stage(Bbl, 32768, 0, o, 1); stage(Bbl, 32768, 1, o, 1);
        PRIO1; MM03(1, Aq); PRIO0; BAR;

        // P3: ahead F4 (T0 A4-7 kk1); MFMA F3; drain reads -> T0 free at P4
        rdA47(0, 1, Aq);
        PRIO1; MM47(0, Ap); PRIO0;
        LGKM0; BAR;

        // P4: stage A(e2)->T0; COUNTED vmcnt retires A(o)+B(o) (ages 3,2 ph);
        //     mid-barrier; ahead F5 (T1 kk0); MFMA F4
        if (g) { stage(Abl, 0, 0, e2, 0); stage(Abl, 0, 1, e2, 0); VMW4; }
        else   { VMW0; }
        BAR;
        rdB(65536, 0); rdA03(65536, 0, Ap);
        PRIO1; MM47(1, Aq); PRIO0; BAR;

        // P5: ahead F6 (T1 kk1); stage B(e2)->T0; MFMA F5
        rdB(65536, 1); rdA03(65536, 1, Aq);
        if (g) { stage(Bbl, 32768, 0, e2, 0); stage(Bbl, 32768, 1, e2, 0); }
        PRIO1; MM03(0, Ap); PRIO0; BAR;

        // P6: ahead F7 (T1 A4-7 kk0); MFMA F6
        rdA47(65536, 0, Ap);
        PRIO1; MM03(1, Aq); PRIO0; BAR;

        // P7: ahead F8 (T1 A4-7 kk1); MFMA F7; drain reads -> T1 free at P8
        rdA47(65536, 1, Aq);
        PRIO1; MM47(0, Ap); PRIO0;
        LGKM0; BAR;

        // P8: stage A(t3)->T1; COUNTED vmcnt retires A(e2)+B(e2);
        //     mid-barrier; ahead F1-next (T0 kk0); MFMA F8
        if (g) { stage(Abl, 0, 0, t3, 1); stage(Abl, 0, 1, t3, 1); VMW4; }
        else   { VMW0; }
        BAR;
        if (g) { rdB(0, 0); rdA03(0, 0, Ap); }
        PRIO1; MM47(1, Aq); PRIO0; BAR;
    }

    // ---- epilogue: swapped layout => lane owns row (fr) x 4 consecutive cols
    const long crow0 = m0 + wm * 128 + fr;
    const long ccol0 = n0 + wn * 64 + fq * 4;
    float4 bv[4];
#pragma unroll
    for (int n = 0; n < 4; ++n) bv[n] = *(const float4*)(bias + ccol0 + n * 16);
#pragma unroll
    for (int m = 0; m < 8; ++m) {
        const long rb = (crow0 + m * 16) * N;
#pragma unroll
        for (int n = 0; n < 4; ++n) {
            float v0 = acc[m][n][0] + bv[n].x;
            float v1 = acc[m][n][1] + bv[n].y;
            float v2 = acc[m][n][2] + bv[n].z;
            float v3 = acc[m][n][3] + bv[n].w;
            if (RELU) {
                v0 = v0 > 0.f ? v0 : 0.f; v1 = v1 > 0.f ? v1 : 0.f;
                v2 = v2 > 0.f ? v2 : 0.f; v3 = v3 > 0.f ? v3 : 0.f;
            }
            if constexpr (sizeof(OT) == 2) {
                uint2 oo;
                oo.x = (unsigned)f2bf(v0) | ((unsigned)f2bf(v1) << 16);
                oo.y = (unsigned)f2bf(v2) | ((unsigned)f2bf(v3) << 16);
                *(uint2*)((unsigned short*)C + rb + ccol0 + n * 16) = oo;
            } else {
                *(float4*)((float*)C + rb + ccol0 + n * 16) =
                    make_float4(v0, v1, v2, v3);
            }
        }
    }
}

// ---------------- launch ----------------
extern "C" void kernel_launch(void* const* d_in, const int* in_sizes, int n_in,
                              void* d_out, int out_size, void* d_ws, size_t ws_size,
                              hipStream_t stream) {
    const float* x1 = (const float*)d_in[0];
    const float* x2 = (const float*)d_in[1];
    const float* Ws = (const float*)d_in[2];   // [4,2048,2048]
    const float* bs = (const float*)d_in[3];   // [4,2048]
    const float* Wl = (const float*)d_in[4];   // [1024,2048]
    const float* bl = (const float*)d_in[5];   // [1024]
    float* out = (float*)d_out;                // [16384,1024]

    char* ws = (char*)d_ws;
    unsigned short* hA  = (unsigned short*)(ws);                  // 64 MiB
    unsigned short* hB  = (unsigned short*)(ws + (67108864L));    // 64 MiB
    unsigned short* Wbf = (unsigned short*)(ws + (134217728L));   // 32 MiB
    unsigned short* Wlb = (unsigned short*)(ws + (167772160L));   // 4 MiB

    cvt_kernel<<<2048, 256, 0, stream>>>(Ws, Wbf, 4L * 2048 * 2048 / 4);
    cvt_kernel<<<512, 256, 0, stream>>>(Wl, Wlb, 1024L * 2048 / 4);

    attn_kernel<<<16384 / 4, 256, 0, stream>>>(x1, x2, hA);

    // MLP: 4x relu GEMM (bf16 ping-pong) + final GEMM (f32 out)
    gemm256<true, unsigned short><<<512, 512, 0, stream>>>(hA, Wbf + 0L * 2048 * 2048, bs + 0 * 2048, hB, 2048, 2048);
    gemm256<true, unsigned short><<<512, 512, 0, stream>>>(hB, Wbf + 1L * 2048 * 2048, bs + 1 * 2048, hA, 2048, 2048);
    gemm256<true, unsigned short><<<512, 512, 0, stream>>>(hA, Wbf + 2L * 2048 * 2048, bs + 2 * 2048, hB, 2048, 2048);
    gemm256<true, unsigned short><<<512, 512, 0, stream>>>(hB, Wbf + 3L * 2048 * 2048, bs + 3 * 2048, hA, 2048, 2048);
    gemm256<false, float><<<256, 512, 0, stream>>>(hA, Wlb, bl, out, 1024, 2048);
}

// Round 8
// 672.373 us; speedup vs baseline: 1.0810x; 1.0268x over previous
//
#include <hip/hip_runtime.h>

// ---------------- types ----------------
typedef __bf16 bf16x8 __attribute__((ext_vector_type(8)));
typedef float f32x4 __attribute__((ext_vector_type(4)));

__device__ __forceinline__ unsigned short f2bf(float f) {
    unsigned int u = __builtin_bit_cast(unsigned int, f);
    u += 0x7FFFu + ((u >> 16) & 1u);
    return (unsigned short)(u >> 16);
}

// ---------------- weight f32 -> bf16 conversion ----------------
__global__ void cvt_kernel(const float* __restrict__ in,
                           unsigned short* __restrict__ out, long n4) {
    long i = (long)blockIdx.x * blockDim.x + threadIdx.x;
    long stride = (long)gridDim.x * blockDim.x;
    for (; i < n4; i += stride) {
        float4 v = ((const float4*)in)[i];
        ushort4 o;
        o.x = f2bf(v.x); o.y = f2bf(v.y); o.z = f2bf(v.z); o.w = f2bf(v.w);
        ((ushort4*)out)[i] = o;
    }
}

// ---------------- fused 2-token attention -> h0 (bf16) ----------------
__global__ __launch_bounds__(256) void attn_kernel(
    const float* __restrict__ x1, const float* __restrict__ x2,
    unsigned short* __restrict__ h) {
    const int D = 1024;
    const int lane = threadIdx.x & 63;
    const int wave = threadIdx.x >> 6;
    const long row = (long)blockIdx.x * 4 + wave;
    const float4* p1 = (const float4*)(x1 + row * D);
    const float4* p2 = (const float4*)(x2 + row * D);
    float4 v1[4], v2[4];
    float s11 = 0.f, s12 = 0.f, s22 = 0.f;
#pragma unroll
    for (int j = 0; j < 4; ++j) {
        v1[j] = p1[lane + 64 * j];
        v2[j] = p2[lane + 64 * j];
        s11 += v1[j].x * v1[j].x + v1[j].y * v1[j].y + v1[j].z * v1[j].z + v1[j].w * v1[j].w;
        s12 += v1[j].x * v2[j].x + v1[j].y * v2[j].y + v1[j].z * v2[j].z + v1[j].w * v2[j].w;
        s22 += v2[j].x * v2[j].x + v2[j].y * v2[j].y + v2[j].z * v2[j].z + v2[j].w * v2[j].w;
    }
#pragma unroll
    for (int off = 1; off < 64; off <<= 1) {
        s11 += __shfl_xor(s11, off);
        s12 += __shfl_xor(s12, off);
        s22 += __shfl_xor(s22, off);
    }
    const float a00 = 1.f / (1.f + expf((s12 - s11) * (1.f / 32.f)));
    const float a10 = 1.f / (1.f + expf((s22 - s12) * (1.f / 32.f)));
    const float a01 = 1.f - a00, a11 = 1.f - a10;
    unsigned short* h0 = h + row * 2048;
#pragma unroll
    for (int j = 0; j < 4; ++j) {
        const int f = lane + 64 * j;
        ushort4 o0, o1;
        o0.x = f2bf(a00 * v1[j].x + a01 * v2[j].x);
        o0.y = f2bf(a00 * v1[j].y + a01 * v2[j].y);
        o0.z = f2bf(a00 * v1[j].z + a01 * v2[j].z);
        o0.w = f2bf(a00 * v1[j].w + a01 * v2[j].w);
        o1.x = f2bf(a10 * v1[j].x + a11 * v2[j].x);
        o1.y = f2bf(a10 * v1[j].y + a11 * v2[j].y);
        o1.z = f2bf(a10 * v1[j].z + a11 * v2[j].z);
        o1.w = f2bf(a10 * v1[j].w + a11 * v2[j].w);
        ((ushort4*)(h0))[f] = o0;
        ((ushort4*)(h0 + 1024))[f] = o1;
    }
}

// ------------- 256x256 8-phase GEMM (m201-exact): C = act(A*Bw^T + b) -------
// BM=BN=256, BK=64, 8 waves (2Mx4N). LDS: 2 slots x {A,B} x {kh0,kh1} K-split
// half-tiles of 16 KiB (256 rows x 32 cols bf16, 64B pitch) = 128 KiB.
// Per phase: {4-or-8 ds_read; stage 1 half (2 gload_lds); BAR; lgkmcnt(0);
// setprio1; 16 MFMA; setprio0; [vmcnt(6) at P4/P8]; BAR}. Steady state: 3
// half-tiles (6 loads) in flight; every waited-on load >=3 phases old.
// st_16x32 swizzle (byte ^= ((byte>>9)&1)<<5) on stage-source AND read addr.
#define BAR   __builtin_amdgcn_s_barrier()
#define LGKM0 asm volatile("s_waitcnt lgkmcnt(0)" ::: "memory")
#define VMW6  asm volatile("s_waitcnt vmcnt(6)" ::: "memory")
#define VMW0  asm volatile("s_waitcnt vmcnt(0)" ::: "memory")
#define PRIO1 __builtin_amdgcn_s_setprio(1)
#define PRIO0 __builtin_amdgcn_s_setprio(0)

#define MMQ(mb)                                                                \
  _Pragma("unroll") for (int n = 0; n < 4; ++n)                                \
  _Pragma("unroll") for (int mq = 0; mq < 4; ++mq)                             \
    acc[(mb) + mq][n] = __builtin_amdgcn_mfma_f32_16x16x32_bf16(               \
        Bf[n], Af[mq], acc[(mb) + mq][n], 0, 0, 0);

template <bool RELU, typename OT>
__global__ __launch_bounds__(512, 2) void gemm256(
    const unsigned short* __restrict__ A,   // [M,K] bf16 (activations)
    const unsigned short* __restrict__ Bw,  // [N,K] bf16 (weights)
    const float* __restrict__ bias,         // [N]
    OT* __restrict__ C,                     // [M,N]
    int N, int K) {
    __shared__ __align__(16) unsigned short lds[65536];  // 128 KiB
    const int tid = threadIdx.x;
    const int lane = tid & 63, wave = tid >> 6;
    const int wm = wave >> 2, wn = wave & 3;
    const int fr = lane & 15, fq = lane >> 4;

    // XCD-swizzled 1D block id -> (bm, bn); M/256 == 64 always here.
    const int cpx = (int)gridDim.x >> 3;
    const int swz = ((int)blockIdx.x & 7) * cpx + ((int)blockIdx.x >> 3);
    const int bm = swz & 63;
    const int bn = swz >> 6;
    const long m0 = (long)bm * 256, n0 = (long)bn * 256;
    const long rowb = (long)K * 2;

    // read addressing: region(T,mat,kh) + row*64 + (fq*16 ^ flip); flip from
    // st_16x32 (bit9 of byte off = bit3 of row = bit3 of fr).
    const int flip = ((fr >> 3) & 1) << 5;
    const int lbase = fr * 64 + ((fq * 16) ^ flip);
    const int aRd = wm * 8192 + lbase;           // + mh*4096 + mq*1024
    const int bRd = 32768 + wn * 4096 + lbase;   // + nf*1024
    const char* ldsc = (const char*)lds;

    // stage addressing: thread writes LDS linear o = L*8192+wave*1024+lane*16;
    // source column pre-swizzled: c2 = (lane&3)*16 ^ ((o>>9)&1)<<5, and
    // bit9(o) = bit3(row) = lane>>5.
    const int srow = wave * 16 + (lane >> 2);              // + L*128
    const int scol = ((lane & 3) << 4) ^ ((lane >> 5) << 5);
    const char* Abl = (const char*)A + m0 * rowb;
    const char* Bbl = (const char*)Bw + n0 * rowb;

    auto stage = [&](const char* mb, int regbase, int kh, int kt) {
#pragma unroll
        for (int L = 0; L < 2; ++L) {
            const int r = L * 128 + srow;
            const char* src = mb + (long)r * rowb + kt * 128 + kh * 64 + scol;
            __builtin_amdgcn_global_load_lds(
                (const __attribute__((address_space(1))) void*)src,
                (__attribute__((address_space(3))) void*)((char*)lds +
                    (regbase + kh * 16384 + L * 8192 + wave * 1024)),
                16, 0, 0);
        }
    };

    f32x4 acc[8][4] = {};
    bf16x8 Bf[4], Af[4];

    auto rdB = [&](int Tb, int kh) {
        const int b = Tb + kh * 16384 + bRd;
#pragma unroll
        for (int nf = 0; nf < 4; ++nf)
            Bf[nf] = *(const bf16x8*)(ldsc + b + nf * 1024);
    };
    auto rdA = [&](int Tb, int kh, int mh) {
        const int b = Tb + kh * 16384 + aRd + mh * 4096;
#pragma unroll
        for (int mq = 0; mq < 4; ++mq)
            Af[mq] = *(const bf16x8*)(ldsc + b + mq * 1024);
    };

    // ---- prologue: t0 (4 halves) -> S0; t1 (3 halves) -> S1; vmcnt(6) ----
    stage(Bbl, 32768, 0, 0); stage(Abl, 0, 0, 0);
    stage(Bbl, 32768, 1, 0); stage(Abl, 0, 1, 0);
    stage(Bbl, 65536 + 32768, 0, 1); stage(Abl, 65536, 0, 1);
    stage(Bbl, 65536 + 32768, 1, 1);
    VMW6;
    BAR;

    const int NT = K >> 6, NIT = NT >> 1;   // 2 K-tiles per iteration
    for (int i = 0; i < NIT; ++i) {
        const int u = 2 * i + 1, t2 = 2 * i + 2, t3 = 2 * i + 3;
        const bool g = (i + 1 < NIT);

        // P1 [S0,kh0,mh0]; stage S1.A.kh1 <- u (last half of tile u)
        rdB(0, 0); rdA(0, 0, 0);
        stage(Abl, 65536, 1, u);
        BAR; LGKM0; PRIO1; MMQ(0); PRIO0; BAR;

        // P2 [S0,kh0,mh1]; stage S0.B.kh0 <- t2 (region freed after P1)
        rdA(0, 0, 1);
        if (g) stage(Bbl, 32768, 0, t2);
        BAR; LGKM0; PRIO1; MMQ(4); PRIO0; BAR;

        // P3 [S0,kh1,mh0]; stage S0.A.kh0 <- t2 (freed after P2)
        rdB(0, 1); rdA(0, 1, 0);
        if (g) stage(Abl, 0, 0, t2);
        BAR; LGKM0; PRIO1; MMQ(0); PRIO0; BAR;

        // P4 [S0,kh1,mh1]; stage S0.B.kh1 <- t2 (freed after P3); vmcnt(6)
        rdA(0, 1, 1);
        if (g) stage(Bbl, 32768, 1, t2);
        BAR; LGKM0; PRIO1; MMQ(4); PRIO0;
        if (g) { VMW6; } else { VMW0; }
        BAR;

        // P5 [S1,kh0,mh0]; stage S0.A.kh1 <- t2 (freed after P4)
        rdB(65536, 0); rdA(65536, 0, 0);
        if (g) stage(Abl, 0, 1, t2);
        BAR; LGKM0; PRIO1; MMQ(0); PRIO0; BAR;

        // P6 [S1,kh0,mh1]; stage S1.B.kh0 <- t3 (freed after P5)
        rdA(65536, 0, 1);
        if (g) stage(Bbl, 65536 + 32768, 0, t3);
        BAR; LGKM0; PRIO1; MMQ(4); PRIO0; BAR;

        // P7 [S1,kh1,mh0]; stage S1.A.kh0 <- t3 (freed after P6)
        rdB(65536, 1); rdA(65536, 1, 0);
        if (g) stage(Abl, 65536, 0, t3);
        BAR; LGKM0; PRIO1; MMQ(0); PRIO0; BAR;

        // P8 [S1,kh1,mh1]; stage S1.B.kh1 <- t3 (freed after P7); vmcnt(6)
        rdA(65536, 1, 1);
        if (g) stage(Bbl, 65536 + 32768, 1, t3);
        BAR; LGKM0; PRIO1; MMQ(4); PRIO0;
        if (g) { VMW6; } else { VMW0; }
        BAR;
    }

    // ---- epilogue: swapped layout => lane owns row (fr) x 4 consecutive cols
    const long crow0 = m0 + wm * 128 + fr;
    const long ccol0 = n0 + wn * 64 + fq * 4;
    float4 bv[4];
#pragma unroll
    for (int n = 0; n < 4; ++n) bv[n] = *(const float4*)(bias + ccol0 + n * 16);
#pragma unroll
    for (int m = 0; m < 8; ++m) {
        const long rb = (crow0 + m * 16) * N;
#pragma unroll
        for (int n = 0; n < 4; ++n) {
            float v0 = acc[m][n][0] + bv[n].x;
            float v1 = acc[m][n][1] + bv[n].y;
            float v2 = acc[m][n][2] + bv[n].z;
            float v3 = acc[m][n][3] + bv[n].w;
            if (RELU) {
                v0 = v0 > 0.f ? v0 : 0.f; v1 = v1 > 0.f ? v1 : 0.f;
                v2 = v2 > 0.f ? v2 : 0.f; v3 = v3 > 0.f ? v3 : 0.f;
            }
            if constexpr (sizeof(OT) == 2) {
                uint2 oo;
                oo.x = (unsigned)f2bf(v0) | ((unsigned)f2bf(v1) << 16);
                oo.y = (unsigned)f2bf(v2) | ((unsigned)f2bf(v3) << 16);
                *(uint2*)((unsigned short*)C + rb + ccol0 + n * 16) = oo;
            } else {
                *(float4*)((float*)C + rb + ccol0 + n * 16) =
                    make_float4(v0, v1, v2, v3);
            }
        }
    }
}

// ---------------- launch ----------------
extern "C" void kernel_launch(void* const* d_in, const int* in_sizes, int n_in,
                              void* d_out, int out_size, void* d_ws, size_t ws_size,
                              hipStream_t stream) {
    const float* x1 = (const float*)d_in[0];
    const float* x2 = (const float*)d_in[1];
    const float* Ws = (const float*)d_in[2];   // [4,2048,2048]
    const float* bs = (const float*)d_in[3];   // [4,2048]
    const float* Wl = (const float*)d_in[4];   // [1024,2048]
    const float* bl = (const float*)d_in[5];   // [1024]
    float* out = (float*)d_out;                // [16384,1024]

    char* ws = (char*)d_ws;
    unsigned short* hA  = (unsigned short*)(ws);                  // 64 MiB
    unsigned short* hB  = (unsigned short*)(ws + (67108864L));    // 64 MiB
    unsigned short* Wbf = (unsigned short*)(ws + (134217728L));   // 32 MiB
    unsigned short* Wlb = (unsigned short*)(ws + (167772160L));   // 4 MiB

    cvt_kernel<<<2048, 256, 0, stream>>>(Ws, Wbf, 4L * 2048 * 2048 / 4);
    cvt_kernel<<<512, 256, 0, stream>>>(Wl, Wlb, 1024L * 2048 / 4);

    attn_kernel<<<16384 / 4, 256, 0, stream>>>(x1, x2, hA);

    // MLP: 4x relu GEMM (bf16 ping-pong) + final GEMM (f32 out)
    gemm256<true, unsigned short><<<512, 512, 0, stream>>>(hA, Wbf + 0L * 2048 * 2048, bs + 0 * 2048, hB, 2048, 2048);
    gemm256<true, unsigned short><<<512, 512, 0, stream>>>(hB, Wbf + 1L * 2048 * 2048, bs + 1 * 2048, hA, 2048, 2048);
    gemm256<true, unsigned short><<<512, 512, 0, stream>>>(hA, Wbf + 2L * 2048 * 2048, bs + 2 * 2048, hB, 2048, 2048);
    gemm256<true, unsigned short><<<512, 512, 0, stream>>>(hB, Wbf + 3L * 2048 * 2048, bs + 3 * 2048, hA, 2048, 2048);
    gemm256<false, float><<<256, 512, 0, stream>>>(hA, Wlb, bl, out, 1024, 2048);
}